// Round 4
// baseline (364.943 us; speedup 1.0000x reference)
//
#include <hip/hip_runtime.h>
#include <hip/hip_fp16.h>

typedef _Float16 half_t;
typedef half_t halfx8 __attribute__((ext_vector_type(8)));
typedef half_t halfx4 __attribute__((ext_vector_type(4)));
typedef float floatx4 __attribute__((ext_vector_type(4)));

#define HID 1024
#define HEADS 16
#define HD 64
#define BATCH 4
#define SEQ 2048
#define MTOT (BATCH * SEQ) /* 8192 */
#define NWELEM (HID * HID) /* 1048576 */

#define MFMA_F16 __builtin_amdgcn_mfma_f32_16x16x32_f16

// Load 8 contiguous elements as halfx8; fp32 source converts on the fly.
__device__ inline halfx8 load8h(const half_t* p) { return *(const halfx8*)p; }
__device__ inline halfx8 load8h(const float* p) {
    floatx4 x = *(const floatx4*)p;
    floatx4 y = *(const floatx4*)(p + 4);
    halfx8 r;
    r[0] = (half_t)x[0]; r[1] = (half_t)x[1];
    r[2] = (half_t)x[2]; r[3] = (half_t)x[3];
    r[4] = (half_t)y[0]; r[5] = (half_t)y[1];
    r[6] = (half_t)y[2]; r[7] = (half_t)y[3];
    return r;
}

// pack two fp32 -> one dword of 2 fp16 (RTN, matches (half_t) cast numerics)
__device__ __forceinline__ uint32_t pack2h(float a, float b) {
    union { half_t h[2]; uint32_t u; } r;
    r.h[0] = (half_t)a; r.h[1] = (half_t)b;
    return r.u;
}

// async 16B global->LDS: LDS dest is wave-uniform base + lane*16 (m104/m173);
// global src is per-lane. size arg must be a literal (16).
__device__ __forceinline__ void gl_lds16(const half_t* g, half_t* lds) {
    __builtin_amdgcn_global_load_lds(
        (const __attribute__((address_space(1))) void*)g,
        (__attribute__((address_space(3))) void*)lds, 16, 0, 0);
}

// ---------------------------------------------------------------------------
// Shared GEMM epilogue.  C/D layout: col = lane&15, row = quad*4 + reg
// [m89-verified].
// MODE 0: fp16 -> [B][H][S][D]   (Q, K)
// MODE 1: fp32 -> flat [M, N]    (final)
// MODE 2: fp16 -> [B][H][D][S]   (V transposed; 8B-aligned halfx4 stores)
// ---------------------------------------------------------------------------
template <int MODE, typename TOut>
__device__ __forceinline__ void epilogue_store(
    const floatx4 (&acc)[4][4], const float* __restrict__ bias,
    TOut* __restrict__ Out, int m0, int n0, int wm, int wn, int quad, int l16)
{
    float bvals[4];
#pragma unroll
    for (int nt = 0; nt < 4; ++nt)
        bvals[nt] = bias[n0 + wn + nt * 16 + l16];

#pragma unroll
    for (int mt = 0; mt < 4; ++mt) {
        const int mbase = m0 + wm + mt * 16 + quad * 4;
#pragma unroll
        for (int nt = 0; nt < 4; ++nt) {
            const int n = n0 + wn + nt * 16 + l16;
            if (MODE == 2) {
                const int b = mbase >> 11, s = mbase & (SEQ - 1);
                const int h = n >> 6, d = n & (HD - 1);
                halfx4 st;
#pragma unroll
                for (int r = 0; r < 4; ++r)
                    st[r] = (half_t)(acc[mt][nt][r] + bvals[nt]);
                *(halfx4*)((half_t*)Out +
                    ((((size_t)b * HEADS + h) * HD + d) << 11) + s) = st;
            } else {
#pragma unroll
                for (int r = 0; r < 4; ++r) {
                    const float v = acc[mt][nt][r] + bvals[nt];
                    const int mm  = mbase + r;
                    if (MODE == 0) {
                        const int b = mm >> 11, s = mm & (SEQ - 1);
                        const int h = n >> 6, d = n & (HD - 1);
                        Out[((((size_t)b * HEADS + h) * SEQ + s) << 6) + d] = (TOut)v;
                    } else {
                        Out[(size_t)mm * HID + n] = (TOut)v;
                    }
                }
            }
        }
    }
}

// ---------------------------------------------------------------------------
// Fast GEMM (fp16 A and W): Out = A @ W^T + bias.
// 128x128 tile, BK=32, 256 thr (4 waves 2x2), mfma 16x16x32 f16.
// 2-PHASE DOUBLE-BUFFERED pipeline (T3 minimal): stage tile k+1 into buf^1
// via global_load_lds BEFORE computing buf's fragments+MFMA; the barrier's
// implicit vmcnt(0) drain lands AFTER ~250cyc of ds_read+MFMA (vs. R2's
// issue-then-immediately-drain exposing full load latency every K-step).
// XCD-aware swizzle: nwg=512 (%8==0); each XCD owns one m-panel x all n.
// ---------------------------------------------------------------------------
template <int MODE, typename TOut>
__global__ __launch_bounds__(256) void gemm16(
    const half_t* __restrict__ A, const half_t* __restrict__ W,
    const float* __restrict__ bias, TOut* __restrict__ Out)
{
    __shared__ half_t As[2][128 * 32];
    __shared__ half_t Bs[2][128 * 32];

    const int tid  = threadIdx.x;
    const int id   = blockIdx.y * gridDim.x + blockIdx.x;
    const int cpx  = (gridDim.x * gridDim.y) >> 3;
    const int swz  = (id & 7) * cpx + (id >> 3);
    const int m0   = (swz >> 3) * 128;          // gridDim.x == 8
    const int n0   = (swz & 7) * 128;
    const int wave = tid >> 6;
    const int lane = tid & 63;
    const int quad = lane >> 4;
    const int l16  = lane & 15;
    const int wm   = (wave >> 1) * 64;
    const int wn   = (wave & 1) * 64;

    // staging map: wave w owns chunks 2w,2w+1 (16 rows each) of A and B.
    // Lane i -> row c0*16 + (i>>2), half-col (i&3)*8 (16 B). HW writes LDS
    // at wave-uniform base + lane*16 -> layout matches linear [128][32].
    const int c0   = wave * 2;
    const int srow = c0 * 16 + (lane >> 2);
    const int scol = (lane & 3) * 8;
    const half_t* aptr0 = A + (size_t)(m0 + srow) * HID + scol;
    const half_t* aptr1 = aptr0 + (size_t)16 * HID;
    const half_t* bptr0 = W + (size_t)(n0 + srow) * HID + scol;
    const half_t* bptr1 = bptr0 + (size_t)16 * HID;

    floatx4 acc[4][4];
    const floatx4 zero4 = {0.f, 0.f, 0.f, 0.f};
#pragma unroll
    for (int mt = 0; mt < 4; ++mt)
#pragma unroll
        for (int nt = 0; nt < 4; ++nt) acc[mt][nt] = zero4;

    auto stage = [&](int buf, int k0) {
        gl_lds16(aptr0 + k0, &As[buf][c0 * 512]);
        gl_lds16(aptr1 + k0, &As[buf][c0 * 512 + 512]);
        gl_lds16(bptr0 + k0, &Bs[buf][c0 * 512]);
        gl_lds16(bptr1 + k0, &Bs[buf][c0 * 512 + 512]);
    };
    auto compute = [&](int buf) {
        halfx8 af[4], bfr[4];
#pragma unroll
        for (int t = 0; t < 4; ++t) {
            af[t]  = *(const halfx8*)&As[buf][(wm + t * 16 + l16) * 32 + quad * 8];
            bfr[t] = *(const halfx8*)&Bs[buf][(wn + t * 16 + l16) * 32 + quad * 8];
        }
#pragma unroll
        for (int mt = 0; mt < 4; ++mt)
#pragma unroll
            for (int nt = 0; nt < 4; ++nt)
                acc[mt][nt] = MFMA_F16(af[mt], bfr[nt], acc[mt][nt], 0, 0, 0);
    };

    stage(0, 0);
    __syncthreads();              // implicit vmcnt(0): tile 0 resident
    for (int k0 = 0; k0 < HID; k0 += 64) {
        stage(1, k0 + 32);        // prefetch while computing buf 0
        compute(0);
        __syncthreads();          // drain: prefetch landed; buf0 reads done
        if (k0 + 64 < HID) stage(0, k0 + 64);
        compute(1);
        __syncthreads();
    }

    epilogue_store<MODE, TOut>(acc, bias, Out, m0, n0, wm, wn, quad, l16);
}

// ---------------------------------------------------------------------------
// Legacy GEMM (fp32 A/W, reg-staged cvt) — fallback if ws too small for the
// fp16 pre-convert path.
// ---------------------------------------------------------------------------
template <int MODE, typename TA, typename TOut>
__global__ __launch_bounds__(256) void gemm_bt(
    const TA* __restrict__ A, const float* __restrict__ W,
    const float* __restrict__ bias, TOut* __restrict__ Out)
{
    __shared__ half_t As[128][40];
    __shared__ half_t Bs[128][40];

    const int tid  = threadIdx.x;
    const int m0   = blockIdx.y * 128;
    const int n0   = blockIdx.x * 128;
    const int wave = tid >> 6;
    const int lane = tid & 63;
    const int quad = lane >> 4;
    const int l16  = lane & 15;
    const int wm   = (wave >> 1) * 64;
    const int wn   = (wave & 1) * 64;
    const int trow = tid >> 1;
    const int tcol = (tid & 1) * 16;

    const TA*    aptr = A + (size_t)(m0 + trow) * HID + tcol;
    const float* bptr = W + (size_t)(n0 + trow) * HID + tcol;

    floatx4 acc[4][4];
    const floatx4 zero4 = {0.f, 0.f, 0.f, 0.f};
#pragma unroll
    for (int mt = 0; mt < 4; ++mt)
#pragma unroll
        for (int nt = 0; nt < 4; ++nt) acc[mt][nt] = zero4;

    for (int k0 = 0; k0 < HID; k0 += 32) {
        halfx8 av0 = load8h(aptr);
        halfx8 av1 = load8h(aptr + 8);
        halfx8 bv0 = load8h(bptr);
        halfx8 bv1 = load8h(bptr + 8);
        aptr += 32;
        bptr += 32;

        __syncthreads();
        *(halfx8*)&As[trow][tcol]     = av0;
        *(halfx8*)&As[trow][tcol + 8] = av1;
        *(halfx8*)&Bs[trow][tcol]     = bv0;
        *(halfx8*)&Bs[trow][tcol + 8] = bv1;
        __syncthreads();

        halfx8 af[4], bfr[4];
#pragma unroll
        for (int t = 0; t < 4; ++t) {
            af[t]  = *(const halfx8*)&As[wm + t * 16 + l16][quad * 8];
            bfr[t] = *(const halfx8*)&Bs[wn + t * 16 + l16][quad * 8];
        }
#pragma unroll
        for (int mt = 0; mt < 4; ++mt)
#pragma unroll
            for (int nt = 0; nt < 4; ++nt)
                acc[mt][nt] = MFMA_F16(af[mt], bfr[nt], acc[mt][nt], 0, 0, 0);
    }

    epilogue_store<MODE, TOut>(acc, bias, Out, m0, n0, wm, wn, quad, l16);
}

// ---------------------------------------------------------------------------
// fp32 -> fp16 conversion kernels (memory-bound, vectorized 8/thread).
// ---------------------------------------------------------------------------
__global__ __launch_bounds__(256) void cvt_act(
    const float* __restrict__ in, half_t* __restrict__ out)
{
    const size_t i = ((size_t)blockIdx.x * 256 + threadIdx.x) * 8;
    *(halfx8*)(out + i) = load8h(in + i);
}

__global__ __launch_bounds__(256) void cvt_w4(
    const float* __restrict__ w0, const float* __restrict__ w1,
    const float* __restrict__ w2, const float* __restrict__ w3,
    half_t* __restrict__ out)
{
    const int t = blockIdx.y;
    const float* src = (t == 0) ? w0 : (t == 1) ? w1 : (t == 2) ? w2 : w3;
    const size_t i = ((size_t)blockIdx.x * 256 + threadIdx.x) * 8;
    *(halfx8*)(out + (size_t)t * NWELEM + i) = load8h(src + i);
}

// ---------------------------------------------------------------------------
// Causal flash attention, fp16, swapped-QK^T (in-register softmax), with
// R2-PROVEN shfl-based cross-lane ops, + T13 defer-max + T14 async staging.
// grid: (B*H, S/128). Block 256 thr / 4 waves; wave w owns q-rows
// [q0+w*32, +32). k-tiles of 64; ktiles = 2*qt+2; fully-masked tiles
// predicated off (barriers stay uniform). V arrives pre-transposed [b][h][d][s].
//
// QK^T = MFMA(K,Q) -> S^T: lane (quad,l16) holds S[kv=k0+nt*16+quad*4+r][q=
// q0+...+l16]; per-lane 16 vals share one q -> softmax = lane-local reduce +
// shfl_xor 16/32.  P packs to fp16 dwords in-register; shfl+select
// redistribution (R2-proven mapping) produces the PV B-frag [n=q][k=kv].
// PV = MFMA(V^T,P) -> O^T; halfx4 epilogue stores.
// ---------------------------------------------------------------------------
__global__ __launch_bounds__(256) void attn_kernel(
    const half_t* __restrict__ Q, const half_t* __restrict__ K,
    const half_t* __restrict__ VT, half_t* __restrict__ O)
{
    __shared__ half_t Ks[64][72];      // [k][d]
    __shared__ half_t Vt[64][72];      // [d][k]

    const int bh  = blockIdx.x;                      // b*HEADS + h
    const int qt  = (gridDim.y - 1) - blockIdx.y;    // heaviest tiles first
    const int q0  = qt * 128;
    const int tid = threadIdx.x;
    const int wave = tid >> 6;
    const int lane = tid & 63;
    const int quad = lane >> 4;
    const int l16  = lane & 15;

    const half_t* Qb  = Q  + (size_t)bh * SEQ * HD;
    const half_t* Kb  = K  + (size_t)bh * SEQ * HD;
    const half_t* VTb = VT + (size_t)bh * HD * SEQ;

    // Q fragments (B-operand of swapped QK^T): B[n=q=l16][k=d=quad*8+j]
    halfx8 aq[2][2];
#pragma unroll
    for (int mt = 0; mt < 2; ++mt) {
        const half_t* p = Qb + (size_t)(q0 + wave * 32 + mt * 16 + l16) * HD + quad * 8;
        aq[mt][0] = *(const halfx8*)p;
        aq[mt][1] = *(const halfx8*)(p + 32);
    }

    const floatx4 zero4 = {0.f, 0.f, 0.f, 0.f};
    floatx4 oaccT[2][4];   // [mt][dt]: lane holds O[q=mt*16+l16][d=dt*16+quad*4+r]
    float mrow[2], lrow[2];
#pragma unroll
    for (int mt = 0; mt < 2; ++mt) {
        mrow[mt] = -3.0e38f;
        lrow[mt] = 0.f;
#pragma unroll
        for (int dt = 0; dt < 4; ++dt) oaccT[mt][dt] = zero4;
    }

    const int srow = tid >> 2;         // 0..63
    const int scol = (tid & 3) * 16;   // 0,16,32,48
    const int ktiles = 2 * qt + 2;

    union U8 { halfx8 h; uint32_t u[4]; };

    // T14 prologue: tile 0 K/V -> regs
    halfx8 nk0, nk1, nv0, nv1;
    {
        const half_t* ksrc = Kb + (size_t)srow * HD + scol;
        nk0 = *(const halfx8*)ksrc;
        nk1 = *(const halfx8*)(ksrc + 8);
        const half_t* vsrc = VTb + (size_t)srow * SEQ + scol;
        nv0 = *(const halfx8*)vsrc;
        nv1 = *(const halfx8*)(vsrc + 8);
    }

    for (int kt = 0; kt < ktiles; ++kt) {
        const int k0 = kt * 64;
        __syncthreads();  // prior iter's Ks/Vt reads done
        *(halfx8*)&Ks[srow][scol]     = nk0;
        *(halfx8*)&Ks[srow][scol + 8] = nk1;
        *(halfx8*)&Vt[srow][scol]     = nv0;
        *(halfx8*)&Vt[srow][scol + 8] = nv1;
        __syncthreads();

        // T14: issue next tile's global loads before this tile's compute;
        // the consuming ds_writes (next iter, after barrier) carry the wait.
        if (kt + 1 < ktiles) {
            const int kn = k0 + 64;
            const half_t* ksrc = Kb + (size_t)(kn + srow) * HD + scol;
            nk0 = *(const halfx8*)ksrc;
            nk1 = *(const halfx8*)(ksrc + 8);
            const half_t* vsrc = VTb + (size_t)srow * SEQ + kn + scol;
            nv0 = *(const halfx8*)vsrc;
            nv1 = *(const halfx8*)(vsrc + 8);
        }

        // wave-uniform activity predicate (no continue: barriers stay uniform)
        const bool active = (k0 <= q0 + wave * 32 + 31);

        if (active) {
            // S^T: sacc[mt][nt] rows kv, cols q (swapped operands)
            floatx4 sacc[2][4];
#pragma unroll
            for (int mt = 0; mt < 2; ++mt)
#pragma unroll
                for (int nt = 0; nt < 4; ++nt) sacc[mt][nt] = zero4;
#pragma unroll
            for (int nt = 0; nt < 4; ++nt) {
                halfx8 bk0 = *(const halfx8*)&Ks[nt * 16 + l16][quad * 8];
                halfx8 bk1 = *(const halfx8*)&Ks[nt * 16 + l16][quad * 8 + 32];
#pragma unroll
                for (int mt = 0; mt < 2; ++mt) {
                    sacc[mt][nt] = MFMA_F16(bk0, aq[mt][0], sacc[mt][nt], 0, 0, 0);
                    sacc[mt][nt] = MFMA_F16(bk1, aq[mt][1], sacc[mt][nt], 0, 0, 0);
                }
            }

            if (kt >= 2 * qt) {  // diagonal region: mask kv > q
#pragma unroll
                for (int mt = 0; mt < 2; ++mt) {
                    const int qg = q0 + wave * 32 + mt * 16 + l16;
#pragma unroll
                    for (int nt = 0; nt < 4; ++nt) {
                        const int kg = k0 + nt * 16 + quad * 4;
#pragma unroll
                        for (int r = 0; r < 4; ++r)
                            if (kg + r > qg) sacc[mt][nt][r] = -1.0e30f;
                    }
                }
            }

            // in-register online softmax (per lane = per q row, 16 vals)
            uint32_t pk[2][4][2];
#pragma unroll
            for (int mt = 0; mt < 2; ++mt) {
                float mx = sacc[mt][0][0];
#pragma unroll
                for (int nt = 0; nt < 4; ++nt)
#pragma unroll
                    for (int r = 0; r < 4; ++r)
                        if (nt | r) mx = fmaxf(mx, sacc[mt][nt][r]);
                mx = fmaxf(mx, __shfl_xor(mx, 16));
                mx = fmaxf(mx, __shfl_xor(mx, 32));

                // T13 defer-max: skip rescale while tile max lags running
                // max by <= 8 (P <= e^8 = 2981 fits fp16; fp32 accum).
                if (!__all(mx <= mrow[mt] + 8.f)) {
                    const float mnew  = fmaxf(mrow[mt], mx);
                    const float alpha = __expf(mrow[mt] - mnew);
                    mrow[mt] = mnew;
                    lrow[mt] *= alpha;
#pragma unroll
                    for (int dt = 0; dt < 4; ++dt) oaccT[mt][dt] *= alpha;
                }

                float rsum = 0.f;
#pragma unroll
                for (int nt = 0; nt < 4; ++nt)
#pragma unroll
                    for (int r = 0; r < 4; ++r) {
                        const float p = __expf(sacc[mt][nt][r] - mrow[mt]);
                        sacc[mt][nt][r] = p;
                        rsum += p;
                    }
#pragma unroll
                for (int nt = 0; nt < 4; ++nt) {
                    pk[mt][nt][0] = pack2h(sacc[mt][nt][0], sacc[mt][nt][1]);
                    pk[mt][nt][1] = pack2h(sacc[mt][nt][2], sacc[mt][nt][3]);
                }
                rsum += __shfl_xor(rsum, 16);
                rsum += __shfl_xor(rsum, 32);
                lrow[mt] += rsum;
            }

            // redistribute P^T C-layout -> PV B-frag [n=q=l16][k=kv=quad*8+j].
            // (R2-proven shfl mapping.)  Target word w of s2 pulls from lane
            // l16+16*(2*(quad&1)+(w>>1)), register nt=2*s2+(quad>>1), h=w&1.
            U8 pb[2][2];  // [mt][s2]
#pragma unroll
            for (int mt = 0; mt < 2; ++mt)
#pragma unroll
                for (int s2 = 0; s2 < 2; ++s2)
#pragma unroll
                    for (int w = 0; w < 4; ++w) {
                        const int src = l16 + ((quad & 1) << 5) + ((w >> 1) << 4);
                        const uint32_t lo =
                            (uint32_t)__shfl((int)pk[mt][2 * s2][w & 1], src, 64);
                        const uint32_t hi =
                            (uint32_t)__shfl((int)pk[mt][2 * s2 + 1][w & 1], src, 64);
                        pb[mt][s2].u[w] = (quad >> 1) ? hi : lo;
                    }

            // PV: O^T = MFMA(A=V^T frag, B=P frag)
#pragma unroll
            for (int s2 = 0; s2 < 2; ++s2)
#pragma unroll
                for (int dt = 0; dt < 4; ++dt) {
                    halfx8 bv = *(const halfx8*)&Vt[dt * 16 + l16][s2 * 32 + quad * 8];
                    oaccT[0][dt] = MFMA_F16(bv, pb[0][s2].h, oaccT[0][dt], 0, 0, 0);
                    oaccT[1][dt] = MFMA_F16(bv, pb[1][s2].h, oaccT[1][dt], 0, 0, 0);
                }
        }
    }

    // epilogue: O^T fragment -> Ob[b][q][h*64+d], halfx4 along d
    const int b = bh >> 4, h = bh & (HEADS - 1);
#pragma unroll
    for (int mt = 0; mt < 2; ++mt) {
        const int q = q0 + wave * 32 + mt * 16 + l16;
#pragma unroll
        for (int dt = 0; dt < 4; ++dt) {
            halfx4 st;
#pragma unroll
            for (int r = 0; r < 4; ++r)
                st[r] = (half_t)(oaccT[mt][dt][r] / lrow[mt]);
            *(halfx4*)(O + (size_t)(b * SEQ + q) * HID +
                       h * HD + dt * 16 + quad * 4) = st;
        }
    }
}

// ---------------------------------------------------------------------------
extern "C" void kernel_launch(void* const* d_in, const int* in_sizes, int n_in,
                              void* d_out, int out_size, void* d_ws, size_t ws_size,
                              hipStream_t stream)
{
    const float* query = (const float*)d_in[0];
    const float* key   = (const float*)d_in[1];
    const float* value = (const float*)d_in[2];
    const float* Wq    = (const float*)d_in[3];
    const float* bq    = (const float*)d_in[4];
    const float* Wk    = (const float*)d_in[5];
    const float* bk    = (const float*)d_in[6];
    const float* Wv    = (const float*)d_in[7];
    const float* bv    = (const float*)d_in[8];
    const float* Wo    = (const float*)d_in[9];
    const float* bo    = (const float*)d_in[10];
    float* out = (float*)d_out;

    // workspace (fp16): Qp, Kp [B][H][S][D]; VpT [B][H][D][S]; Ob [M][HID];
    // W16 [4][HID][HID].  Fast path needs 75.5 MB (proven R1/R2); fall back
    // to the fp32-staged GEMM if the extra 8.4 MB for W16 isn't there.  The
    // single fp16-activation staging buffer aliases the Ob slot (dead until
    // attn runs): conv->GEMM pairs are serialized per activation.
    const size_t NE = (size_t)MTOT * HID;
    half_t* Qp  = (half_t*)d_ws;
    half_t* Kp  = Qp  + NE;
    half_t* VpT = Kp  + NE;
    half_t* Ob  = VpT + NE;
    half_t* W16 = Ob  + NE;
    const size_t need = (4 * NE + 4 * (size_t)NWELEM) * sizeof(half_t);

    dim3 gg(HID / 128, MTOT / 128);     // (8, 64)
    dim3 ga(BATCH * HEADS, SEQ / 128);  // (64, 16)

    if (ws_size >= need) {
        half_t* act16 = Ob;  // Ob slot reused as staging pre-attn
        const unsigned actBlocks = (unsigned)(NE / 2048);      // 4096
        const unsigned wBlocks   = (unsigned)(NWELEM / 2048);  // 512

        cvt_w4<<<dim3(wBlocks, 4), 256, 0, stream>>>(Wq, Wk, Wv, Wo, W16);

        cvt_act<<<actBlocks, 256, 0, stream>>>(query, act16);
        gemm16<0, half_t><<<gg, 256, 0, stream>>>(act16, W16, bq, Qp);
        cvt_act<<<actBlocks, 256, 0, stream>>>(key, act16);
        gemm16<0, half_t><<<gg, 256, 0, stream>>>(act16, W16 + NWELEM, bk, Kp);
        cvt_act<<<actBlocks, 256, 0, stream>>>(value, act16);
        gemm16<2, half_t><<<gg, 256, 0, stream>>>(act16, W16 + 2 * (size_t)NWELEM, bv, VpT);

        attn_kernel<<<ga, 256, 0, stream>>>(Qp, Kp, VpT, Ob);

        gemm16<1, float><<<gg, 256, 0, stream>>>(Ob, W16 + 3 * (size_t)NWELEM, bo, out);
    } else {
        // legacy fallback path
        gemm_bt<0, float, half_t><<<gg, 256, 0, stream>>>(query, Wq, bq, Qp);
        gemm_bt<0, float, half_t><<<gg, 256, 0, stream>>>(key,   Wk, bk, Kp);
        gemm_bt<2, float, half_t><<<gg, 256, 0, stream>>>(value, Wv, bv, VpT);
        attn_kernel<<<ga, 256, 0, stream>>>(Qp, Kp, VpT, Ob);
        gemm_bt<1, half_t, float><<<gg, 256, 0, stream>>>(Ob, Wo, bo, out);
    }
}